// Round 6
// baseline (207.482 us; speedup 1.0000x reference)
//
#include <hip/hip_runtime.h>

#define BTOT 4194304
#define MPW 4   // 64-row macro-groups per wave

typedef __attribute__((ext_vector_type(4))) float f32x4;
typedef __attribute__((ext_vector_type(8))) short bf16x8;

#define KLOG 2.88539008177792681472f  // 2*log2(e)
#define NTAB 256
#define TDOM 4.8f
#define TSCALE ((float)NTAB / (2.0f * TDOM))   // 26.6667 per unit z
#define TOFF  ((float)NTAB / 2.0f)             // 128: index = TSCALE*z + TOFF

__device__ __forceinline__ short f2bf(float f) {   // RNE, setup only
  union { float f; unsigned u; } v; v.f = f;
  unsigned u = v.u;
  unsigned r = (u + 0x7FFFu + ((u >> 16) & 1u)) >> 16;
  return (short)r;
}
__device__ __forceinline__ float bf2f(short s) {
  union { unsigned u; float f; } v; v.u = ((unsigned)(unsigned short)s) << 16;
  return v.f;
}

// exp2-based tanh, used ONLY for table build (setup).
__device__ __forceinline__ float tanh_hw(float z) {
  float t = __builtin_amdgcn_exp2f(KLOG * z);
  float r = __builtin_amdgcn_rcpf(1.0f + t);
  return __builtin_fmaf(-2.0f, r, 1.0f);
}

// LUT tanh: input is the PRE-SCALED index fi = TSCALE*z + TOFF (folded into
// weights/bias/MFMA operands). 7 full-rate VALU + 1 ds_read_b64.
__device__ __forceinline__ float tanh_lut(float fi, const float2* ptab) {
  fi = fminf(fmaxf(fi, 0.0f), (float)NTAB);
  int i = (int)fi;              // trunc == floor (fi >= 0)
  float fr = fi - (float)i;
  float2 e = ptab[i];           // (value, delta-to-next)
  return __builtin_fmaf(e.y, fr, e.x);
}

// One-instruction RNE pack of 2 floats -> packed bf16 pair.
__device__ __forceinline__ unsigned cvt_pk(float lo, float hi) {
  unsigned r;
  asm("v_cvt_pk_bf16_f32 %0, %1, %2" : "=v"(r) : "v"(lo), "v"(hi));
  return r;
}
__device__ __forceinline__ bf16x8 pack8(const float* h) {
  union { unsigned w[4]; bf16x8 v; } U;
  #pragma unroll
  for (int jw = 0; jw < 4; ++jw) U.w[jw] = cvt_pk(h[2 * jw], h[2 * jw + 1]);
  return U.v;
}

__global__ __launch_bounds__(256, 4)
void damping_kernel(const float* __restrict__ x,
                    const float* __restrict__ w_d1, const float* __restrict__ w_d2,
                    const float* __restrict__ w_d3, const float* __restrict__ w_o1,
                    const float* __restrict__ w_o2, const float* __restrict__ w_o3,
                    const float* __restrict__ b_d1, const float* __restrict__ b_d2,
                    const float* __restrict__ b_d3, const float* __restrict__ b_o1,
                    const float* __restrict__ b_o2, const float* __restrict__ b_o3,
                    float* __restrict__ out)
{
  // ---- tanh table: 256 linear-interp intervals over [-4.8, 4.8] ----
  __shared__ float  vtab[NTAB + 2];
  __shared__ float2 ptab[NTAB + 1];
  for (int i = threadIdx.x; i < NTAB + 2; i += 256) {
    float z = __builtin_fmaf((float)i, 1.0f / TSCALE, -TDOM);
    vtab[i] = tanh_hw(z);
  }
  __syncthreads();
  for (int i = threadIdx.x; i < NTAB + 1; i += 256) {
    ptab[i] = make_float2(vtab[i], vtab[i + 1] - vtab[i]);
  }
  __syncthreads();

  const int tid  = blockIdx.x * blockDim.x + threadIdx.x;
  const int wave = tid >> 6;
  const int l    = threadIdx.x & 63;
  const int g    = l >> 4;      // k-group 0..3
  const int c16  = l & 15;      // row-in-tile / A-row / C-col
  const int kbase = g * 8;

  // ---- per-lane constants ----
  // Layer-1 weights pre-scaled by TSCALE, bias also +TOFF: preact == LUT index.
  float W0[8], W1[8], B1[8];
  #pragma unroll
  for (int j = 0; j < 8; ++j) {
    int f = kbase + j;
    if (f < 16) { W0[j] = TSCALE * w_d1[f];      W1[j] = TSCALE * w_d1[16 + f];      B1[j] = TSCALE * b_d1[f] + TOFF; }
    else        { W0[j] = TSCALE * w_o1[f - 16]; W1[j] = TSCALE * w_o1[16 + f - 16]; B1[j] = TSCALE * b_o1[f - 16] + TOFF; }
  }
  // Layer-2 A = (TSCALE*w2)^T zero-padded per net, hi/lo split (weights only).
  bf16x8 Adh, Adl, Aoh, Aol;
  #pragma unroll
  for (int j = 0; j < 8; ++j) {
    int k = kbase + j;
    float ad = (k < 16)  ? TSCALE * w_d2[k * 16 + c16]        : 0.0f;
    float ao = (k >= 16) ? TSCALE * w_o2[(k - 16) * 16 + c16] : 0.0f;
    short adh = f2bf(ad); Adh[j] = adh; Adl[j] = f2bf(ad - bf2f(adh));
    short aoh = f2bf(ao); Aoh[j] = aoh; Aol[j] = f2bf(ao - bf2f(aoh));
  }
  // Layer-2 C-init = TSCALE*bias + TOFF: MFMA acc == LUT index directly.
  f32x4 Cd0, Co0;
  #pragma unroll
  for (int i = 0; i < 4; ++i) {
    int f = g * 4 + i;
    Cd0[i] = TSCALE * b_d2[f] + TOFF; Co0[i] = TSCALE * b_o2[f] + TOFF;
  }

  // Layer-3 A-operand, 4 tile-variants (unscaled; outputs a,b,c used raw).
  const int rr = c16 & 3, tt = c16 >> 2;
  bf16x8 A3h[4];
  #pragma unroll
  for (int t = 0; t < 4; ++t) {
    #pragma unroll
    for (int j = 0; j < 8; ++j) {
      float val = 0.0f;
      if (t == tt) {
        if (rr == 0 && j < 4)  val = w_d3[(4 * g + j) * 2 + 0];
        if (rr == 1 && j < 4)  val = w_d3[(4 * g + j) * 2 + 1];
        if (rr == 2 && j >= 4) val = w_o3[4 * g + j - 4];
      }
      A3h[t][j] = f2bf(val);
    }
  }
  const float b30 = b_d3[0], b31 = b_d3[1], b3o = b_o3[0];

  const float2* x2 = (const float2*)x;

  for (int m = 0; m < MPW; ++m) {
    const int mbase = (wave * MPW + m) * 64;

    // preload the 4 x-tiles
    float2 xv4[4];
    #pragma unroll
    for (int t = 0; t < 4; ++t)
      xv4[t] = x2[mbase + t * 16 + c16];

    f32x4 acc3;
    acc3[0] = b30; acc3[1] = b31; acc3[2] = b3o; acc3[3] = 0.0f;

    #pragma unroll
    for (int t = 0; t < 4; ++t) {
      const float2 xv = xv4[t];

      // layer 1: fma to LUT-index, then table tanh (8 feats/lane)
      float h[8];
      #pragma unroll
      for (int j = 0; j < 8; ++j)
        h[j] = tanh_lut(__builtin_fmaf(xv.y, W1[j], __builtin_fmaf(xv.x, W0[j], B1[j])), ptab);

      bf16x8 b1f = pack8(h);   // 4 cvt_pk

      // layer 2: weights hi/lo x activation single (4 MFMA); acc == LUT index
      f32x4 accd = Cd0, acco = Co0;
      accd = __builtin_amdgcn_mfma_f32_16x16x32_bf16(Adh, b1f, accd, 0, 0, 0);
      accd = __builtin_amdgcn_mfma_f32_16x16x32_bf16(Adl, b1f, accd, 0, 0, 0);
      acco = __builtin_amdgcn_mfma_f32_16x16x32_bf16(Aoh, b1f, acco, 0, 0, 0);
      acco = __builtin_amdgcn_mfma_f32_16x16x32_bf16(Aol, b1f, acco, 0, 0, 0);

      // layer-2 tanh via table
      float h2[8];
      #pragma unroll
      for (int i = 0; i < 4; ++i) {
        h2[i]     = tanh_lut(accd[i], ptab);
        h2[4 + i] = tanh_lut(acco[i], ptab);
      }
      bf16x8 b3f = pack8(h2);  // 4 cvt_pk

      // layer 3: accumulate rows 4t..4t+2 of [a_pre,b_pre,c] (1 MFMA)
      acc3 = __builtin_amdgcn_mfma_f32_16x16x32_bf16(A3h[t], b3f, acc3, 0, 0, 0);
    }

    // epilogue once per 64 rows: lane l holds (a_pre,b_pre,c) for row mbase+l
    const float2 xs = x2[mbase + l];
    float a = (fmaxf(acc3[0], 0.0f) + 0.001f) * xs.x;
    float b = (fmaxf(acc3[1], 0.0f) + 0.001f) * xs.y;
    float c = acc3[2];
    float D0 = a * __builtin_fmaf(a, xs.x, c * xs.y);
    float s  = __builtin_fmaf(c, c, b * b);
    float D1 = __builtin_fmaf(a * c, xs.x, s * xs.y);
    ((float2*)out)[mbase + l] = make_float2(D0, D1);  // coalesced 512B/wave
  }
}

extern "C" void kernel_launch(void* const* d_in, const int* in_sizes, int n_in,
                              void* d_out, int out_size, void* d_ws, size_t ws_size,
                              hipStream_t stream) {
  const float* x    = (const float*)d_in[0];
  const float* w_d1 = (const float*)d_in[1];
  const float* w_d2 = (const float*)d_in[2];
  const float* w_d3 = (const float*)d_in[3];
  const float* w_o1 = (const float*)d_in[4];
  const float* w_o2 = (const float*)d_in[5];
  const float* w_o3 = (const float*)d_in[6];
  const float* b_d1 = (const float*)d_in[7];
  const float* b_d2 = (const float*)d_in[8];
  const float* b_d3 = (const float*)d_in[9];
  const float* b_o1 = (const float*)d_in[10];
  const float* b_o2 = (const float*)d_in[11];
  const float* b_o3 = (const float*)d_in[12];
  float* out = (float*)d_out;

  const int waves  = BTOT / (64 * MPW);  // 16384
  const int blocks = waves / 4;          // 4096 blocks of 256 threads
  damping_kernel<<<blocks, 256, 0, stream>>>(x, w_d1, w_d2, w_d3, w_o1, w_o2, w_o3,
                                             b_d1, b_d2, b_d3, b_o1, b_o2, b_o3, out);
}